// Round 4
// baseline (41996.826 us; speedup 1.0000x reference)
//
#include <hip/hip_runtime.h>

#define S_LEN 65536
#define HDIM 128

typedef _Float16 half2_t __attribute__((ext_vector_type(2)));
typedef _Float16 half8_t __attribute__((ext_vector_type(8)));
typedef float f32x4 __attribute__((ext_vector_type(4)));

__device__ __forceinline__ float sigm(float x) {
    return 1.0f / (1.0f + __expf(-x));
}
__device__ __forceinline__ float tanh_fast(float x) {
    return 2.0f / (1.0f + __expf(-2.0f * x)) - 1.0f;
}
__device__ __forceinline__ float dot2(half2_t a, half2_t b, float c) {
#if __has_builtin(__builtin_amdgcn_fdot2)
    return __builtin_amdgcn_fdot2(a, b, c, false);
#else
    return fmaf((float)a.x, (float)b.x, fmaf((float)a.y, (float)b.y, c));
#endif
}

// Raw workgroup barrier: drain LDS only (lgkmcnt). Compute waves have NO
// global ops in their loop, so they never wait on vmcnt.
#define WG_BARRIER() do {                                         \
    asm volatile("s_waitcnt lgkmcnt(0)" ::: "memory");            \
    __builtin_amdgcn_s_barrier();                                 \
    asm volatile("" ::: "memory");                                \
} while (0)

// ================= Kernel 1: dot2 recurrence + producer wave ==============
// R10 post-mortem of R7-R9: three different compute formulations all land at
// ~1435-1512 cy/step; removing ALL MFMA work changed nothing. The invariant
// is a per-step global load (x prefetch) + global store (h_hist) issued by
// the critical-path wave: vmcnt is per-wave and order-based, so the
// compiler's s_waitcnt vmcnt(N) before the x use serializes on h_hist STORE
// retirement through L2 (~400-600cy) -- the hidden ~700cy/step.
// Fix: compute waves (0-3) do ZERO VMEM in the loop. A 5th producer wave:
//   (a) stages x into a 512-step circular LDS buffer in 256-step blocks,
//       T14-split (global loads at block start, ds_write 128 steps later);
//   (b) drains h_t from the LDS ping-pong to h_hist one step behind
//       (ds_read_b32 + coalesced global_store_dword, its own vmcnt domain).
// Compute waves read x via broadcast ds_read_b64; their only waits are lgkm.
// Also: weights pre-split into 128 pinned half2 VGPRs; h pairs extracted
// with __builtin_shufflevector (even-aligned subregister extracts) so dot2
// operands cost zero construction VALU.
// Layout: wave w owns h[32w..32w+32); lane = (half=l>>5, j=l&31); each lane
// holds K-half [64*half,+64) of all 4 gate rows of h[32w+j]; 128 dot2/lane
// per step (MAC-optimal); K-halves combined by 4 shfl_xor(32); activations
// redundantly in both halves (uniform); lanes<32 write h.
__global__ __launch_bounds__(320)
__attribute__((amdgpu_waves_per_eu(2)))
void lstm_seq_dot2(const float* __restrict__ x,
                   const float* __restrict__ h0,
                   const float* __restrict__ c0,
                   const float* __restrict__ W_ih,
                   const float* __restrict__ W_hh,
                   const float* __restrict__ b_ih,
                   const float* __restrict__ b_hh,
                   _Float16* __restrict__ h_hist)
{
    __shared__ __align__(16) _Float16 h_buf[2][HDIM];  // ping-pong h_t (f16)
    __shared__ __align__(16) float xb[1024];           // 512-step circular x

    const int tid  = threadIdx.x;       // 0..319, 5 waves
    const int lane = tid & 63;
    const int w    = tid >> 6;          // 0..3 compute, 4 producer

    if (w < 4) {
        // =================== COMPUTE WAVES ===================
        const int j    = lane & 31;         // h element within slice
        const int half = lane >> 5;         // k-half
        const int hidx = w * 32 + j;
        const int k0   = half * 64;

        // ---- W fragments: 4 gates x 32 half2 = 128 pinned VGPRs ----
#define LW2(g, k2) \
        half2_t w_##g##_##k2; { \
            const float* s_ = W_hh + (size_t)(hidx + 128 * (g)) * HDIM \
                                   + k0 + 2 * (k2); \
            w_##g##_##k2 = (half2_t){ (_Float16)s_[0], (_Float16)s_[1] }; \
            asm volatile("" : "+v"(w_##g##_##k2)); }
#define LWG(g) \
        LW2(g,0)  LW2(g,1)  LW2(g,2)  LW2(g,3)  LW2(g,4)  LW2(g,5)  LW2(g,6)  LW2(g,7)  \
        LW2(g,8)  LW2(g,9)  LW2(g,10) LW2(g,11) LW2(g,12) LW2(g,13) LW2(g,14) LW2(g,15) \
        LW2(g,16) LW2(g,17) LW2(g,18) LW2(g,19) LW2(g,20) LW2(g,21) LW2(g,22) LW2(g,23) \
        LW2(g,24) LW2(g,25) LW2(g,26) LW2(g,27) LW2(g,28) LW2(g,29) LW2(g,30) LW2(g,31)
        LWG(0) LWG(1) LWG(2) LWG(3)
#undef LWG
#undef LW2

        // ---- Per-h-element state (replicated in both k-halves) ----
        const int r0 = hidx, r1 = hidx + 128, r2 = hidx + 256, r3 = hidx + 384;
        const float wi00 = W_ih[2 * r0], wi01 = W_ih[2 * r0 + 1];
        const float wi10 = W_ih[2 * r1], wi11 = W_ih[2 * r1 + 1];
        const float wi20 = W_ih[2 * r2], wi21 = W_ih[2 * r2 + 1];
        const float wi30 = W_ih[2 * r3], wi31 = W_ih[2 * r3 + 1];
        const float bs0 = b_ih[r0] + b_hh[r0];
        const float bs1 = b_ih[r1] + b_hh[r1];
        const float bs2 = b_ih[r2] + b_hh[r2];
        const float bs3 = b_ih[r3] + b_hh[r3];
        float c = c0[hidx];

        if (tid < HDIM) h_buf[0][tid] = (_Float16)h0[tid];
        __syncthreads();

        const half8_t* hb0 = ((const half8_t*)h_buf[0]) + 8 * half;
        const half8_t* hb1 = ((const half8_t*)h_buf[1]) + 8 * half;

        // even-aligned pair extract: subregister, no VALU
#define PR(hv, p) ((half2_t)__builtin_shufflevector((hv), (hv), 2*(p), 2*(p)+1))

#define GDOT(g, dst) { \
        float A_=0.f, B_=0.f, C_=0.f, D_=0.f; \
        A_=dot2(w_##g##_0 , PR(hv0,0), A_); B_=dot2(w_##g##_1 , PR(hv0,1), B_); \
        C_=dot2(w_##g##_2 , PR(hv0,2), C_); D_=dot2(w_##g##_3 , PR(hv0,3), D_); \
        A_=dot2(w_##g##_4 , PR(hv1,0), A_); B_=dot2(w_##g##_5 , PR(hv1,1), B_); \
        C_=dot2(w_##g##_6 , PR(hv1,2), C_); D_=dot2(w_##g##_7 , PR(hv1,3), D_); \
        A_=dot2(w_##g##_8 , PR(hv2,0), A_); B_=dot2(w_##g##_9 , PR(hv2,1), B_); \
        C_=dot2(w_##g##_10, PR(hv2,2), C_); D_=dot2(w_##g##_11, PR(hv2,3), D_); \
        A_=dot2(w_##g##_12, PR(hv3,0), A_); B_=dot2(w_##g##_13, PR(hv3,1), B_); \
        C_=dot2(w_##g##_14, PR(hv3,2), C_); D_=dot2(w_##g##_15, PR(hv3,3), D_); \
        A_=dot2(w_##g##_16, PR(hv4,0), A_); B_=dot2(w_##g##_17, PR(hv4,1), B_); \
        C_=dot2(w_##g##_18, PR(hv4,2), C_); D_=dot2(w_##g##_19, PR(hv4,3), D_); \
        A_=dot2(w_##g##_20, PR(hv5,0), A_); B_=dot2(w_##g##_21, PR(hv5,1), B_); \
        C_=dot2(w_##g##_22, PR(hv5,2), C_); D_=dot2(w_##g##_23, PR(hv5,3), D_); \
        A_=dot2(w_##g##_24, PR(hv6,0), A_); B_=dot2(w_##g##_25, PR(hv6,1), B_); \
        C_=dot2(w_##g##_26, PR(hv6,2), C_); D_=dot2(w_##g##_27, PR(hv6,3), D_); \
        A_=dot2(w_##g##_28, PR(hv7,0), A_); B_=dot2(w_##g##_29, PR(hv7,1), B_); \
        C_=dot2(w_##g##_30, PR(hv7,2), C_); D_=dot2(w_##g##_31, PR(hv7,3), D_); \
        dst = (A_ + B_) + (C_ + D_); }

        // gate-major: f,i,g first so shfl+sigm overlap remaining dots and
        // the c-chain starts before o finishes.
#define STEP(T, RB, WB) { \
        const half8_t* hb_ = (RB); \
        half8_t hv0 = hb_[0], hv1 = hb_[1], hv2 = hb_[2], hv3 = hb_[3]; \
        half8_t hv4 = hb_[4], hv5 = hb_[5], hv6 = hb_[6], hv7 = hb_[7]; \
        const float2 xv = *(const float2*)(xb + 2 * ((T) & 511)); \
        float s0, s1, s2, s3; \
        GDOT(1, s1)  s1 += __shfl_xor(s1, 32, 64); \
        GDOT(0, s0)  s0 += __shfl_xor(s0, 32, 64); \
        GDOT(2, s2)  s2 += __shfl_xor(s2, 32, 64); \
        GDOT(3, s3)  s3 += __shfl_xor(s3, 32, 64); \
        const float gf = sigm(fmaf(wi10, xv.x, fmaf(wi11, xv.y, bs1)) + s1); \
        const float gi = sigm(fmaf(wi00, xv.x, fmaf(wi01, xv.y, bs0)) + s0); \
        const float gg = tanh_fast(fmaf(wi20, xv.x, fmaf(wi21, xv.y, bs2)) + s2); \
        const float go = sigm(fmaf(wi30, xv.x, fmaf(wi31, xv.y, bs3)) + s3); \
        c = fmaf(gf, c, gi * gg); \
        const float hval = go * tanh_fast(c); \
        const _Float16 hf_ = (_Float16)hval; \
        if (lane < 32) (WB)[hidx] = hf_; \
        WG_BARRIER(); }

        #pragma unroll 1
        for (int t = 0; t < S_LEN; t += 2) {
            STEP(t,     hb0, h_buf[1])
            STEP(t + 1, hb1, h_buf[0])
        }
#undef STEP
#undef GDOT
#undef PR
    } else {
        // =================== PRODUCER WAVE ===================
        // Prologue: stage blocks 0,1 (steps 0..511 = 4KB = 256 float4).
        {
            const float4* src = (const float4*)x + lane;
            float4 a0 = src[0], a1 = src[64], a2 = src[128], a3 = src[192];
            float4* dst = (float4*)xb + lane;
            dst[0] = a0; dst[64] = a1; dst[128] = a2; dst[192] = a3;
        }
        __syncthreads();

        float4 xs0 = {0.f, 0.f, 0.f, 0.f}, xs1 = xs0;

        #pragma unroll 1
        for (int t = 0; t < S_LEN; ++t) {
            const int r   = t & 255;
            const int blk = t >> 8;
            if (r == 0 && blk >= 1 && blk < 255) {
                // issue loads for block blk+1 (consumed starting t+256)
                const float4* src = (const float4*)x
                                  + (size_t)(blk + 1) * 128 + lane;
                xs0 = src[0]; xs1 = src[64];
            }
            if (r == 128 && blk >= 1 && blk < 255) {
                // write-late: loads from 128 steps ago are long complete
                float4* dst = (float4*)xb + (((blk + 1) & 1) * 128) + lane;
                dst[0] = xs0; dst[64] = xs1;
            }
            if (t > 0) {
                // h_{t-1} sits in h_buf[t&1]; copy to h_hist (coalesced)
                const uint32_t hv_ =
                    *(const uint32_t*)((const char*)(h_buf[t & 1]) + 4 * lane);
                ((uint32_t*)h_hist)[(size_t)(t - 1) * 64 + lane] = hv_;
            }
            WG_BARRIER();
        }
        // final h_{S-1} is in h_buf[0]
        const uint32_t hv_ =
            *(const uint32_t*)((const char*)(h_buf[0]) + 4 * lane);
        ((uint32_t*)h_hist)[(size_t)(S_LEN - 1) * 64 + lane] = hv_;
    }
}

// ================= Kernel 2: out[t] = tanh(h_t).W_out + b =================
__global__ __launch_bounds__(256)
void out_proj(const _Float16* __restrict__ h_hist,
              const float* __restrict__ W_out,
              const float* __restrict__ b_out,
              float* __restrict__ out)
{
    const int lane  = threadIdx.x & 63;
    const int gwave = (blockIdx.x * 256 + threadIdx.x) >> 6;
    const int nwave = (gridDim.x * 256) >> 6;

    const float wo0 = W_out[2 * lane + 0];
    const float wo1 = W_out[2 * lane + 1];
    const float bout = b_out[0];

    for (int t = gwave; t < S_LEN; t += nwave) {
        half2_t hv = ((const half2_t*)(h_hist + t * HDIM))[lane];
        float p = tanh_fast((float)hv.x) * wo0 + tanh_fast((float)hv.y) * wo1;
        #pragma unroll
        for (int off = 32; off > 0; off >>= 1)
            p += __shfl_xor(p, off, 64);
        if (lane == 0) out[t] = p + bout;
    }
}

// ================= Fallback: fused single kernel (ws too small) ===========
#define H_HI_OFF 144
__global__ __launch_bounds__(1024)
__attribute__((amdgpu_waves_per_eu(4, 4)))
void lstm_seq_full(const float* __restrict__ x,
                   const float* __restrict__ h0,
                   const float* __restrict__ c0,
                   const float* __restrict__ W_ih,
                   const float* __restrict__ W_hh,
                   const float* __restrict__ b_ih,
                   const float* __restrict__ b_hh,
                   const float* __restrict__ W_out,
                   const float* __restrict__ b_out,
                   float* __restrict__ out)
{
    __shared__ __align__(16) unsigned char h_raw[2 * H_HI_OFF];
    __shared__ float gates_part[2 * 512];
    __shared__ float red_sh[2];

    const int tid  = threadIdx.x;
    const int j    = tid >> 1;
    const int half = tid & 1;

    const float2* wr2 = (const float2*)(W_hh + j * HDIM + half * 64);
#define WDEF(i) half2_t W##i; { float2 t = wr2[i]; \
        W##i.x = (_Float16)t.x; W##i.y = (_Float16)t.y; } \
        asm volatile("" : "+v"(W##i));
    WDEF(0)  WDEF(1)  WDEF(2)  WDEF(3)  WDEF(4)  WDEF(5)  WDEF(6)  WDEF(7)
    WDEF(8)  WDEF(9)  WDEF(10) WDEF(11) WDEF(12) WDEF(13) WDEF(14) WDEF(15)
    WDEF(16) WDEF(17) WDEF(18) WDEF(19) WDEF(20) WDEF(21) WDEF(22) WDEF(23)
    WDEF(24) WDEF(25) WDEF(26) WDEF(27) WDEF(28) WDEF(29) WDEF(30) WDEF(31)
#undef WDEF

    float wih0 = 0.0f, wih1 = 0.0f, bias = 0.0f;
    if (half == 0) {
        wih0 = W_ih[2 * j + 0];
        wih1 = W_ih[2 * j + 1];
        bias = b_ih[j] + b_hh[j];
    }

    float c = 0.0f, wout = 0.0f;
    _Float16* hw = (_Float16*)(h_raw + ((tid < 64) ? 2 * tid
                                                   : H_HI_OFF + 2 * (tid - 64)));
    if (tid < HDIM) {
        c = c0[tid];
        wout = W_out[tid];
        *hw = (_Float16)h0[tid];
    }
    const float bout = b_out[0];
    __syncthreads();

    const float2* xp = (const float2*)x;
    float2 xcur = xp[0];
    const half8_t* hp = (const half8_t*)(h_raw + half * H_HI_OFF);

    #pragma unroll 1
    for (int t = 0; t < S_LEN; ++t) {
        const int tn = (t + 1 < S_LEN) ? (t + 1) : (S_LEN - 1);
        float2 xnext = xp[tn];

        float a0 = fmaf(wih0, xcur.x, fmaf(wih1, xcur.y, bias));
        float a1 = 0.0f, a2 = 0.0f, a3 = 0.0f;

#define CHUNK(cc, w0_, w1_, w2_, w3_) {                         \
        half8_t hv = hp[cc];                                    \
        half2_t p0 = { hv[0], hv[1] };                          \
        half2_t p1 = { hv[2], hv[3] };                          \
        half2_t p2 = { hv[4], hv[5] };                          \
        half2_t p3 = { hv[6], hv[7] };                          \
        a0 = dot2(w0_, p0, a0);                                 \
        a1 = dot2(w1_, p1, a1);                                 \
        a2 = dot2(w2_, p2, a2);                                 \
        a3 = dot2(w3_, p3, a3); }
        CHUNK(0, W0,  W1,  W2,  W3)
        CHUNK(1, W4,  W5,  W6,  W7)
        CHUNK(2, W8,  W9,  W10, W11)
        CHUNK(3, W12, W13, W14, W15)
        CHUNK(4, W16, W17, W18, W19)
        CHUNK(5, W20, W21, W22, W23)
        CHUNK(6, W24, W25, W26, W27)
        CHUNK(7, W28, W29, W30, W31)
#undef CHUNK

        gates_part[half * 512 + j] = (a0 + a1) + (a2 + a3);
        __syncthreads();

        if (tid < HDIM) {
            float gi = sigm(gates_part[tid]            + gates_part[tid + 512]);
            float gf = sigm(gates_part[tid + 128]      + gates_part[tid + 640]);
            float gg = tanh_fast(gates_part[tid + 256] + gates_part[tid + 768]);
            float go = sigm(gates_part[tid + 384]      + gates_part[tid + 896]);
            c = fmaf(gf, c, gi * gg);
            float h = go * tanh_fast(c);
            *hw = (_Float16)h;

            float p = tanh_fast(h) * wout;
            #pragma unroll
            for (int off = 32; off > 0; off >>= 1)
                p += __shfl_xor(p, off, 64);
            if ((tid & 63) == 0) red_sh[tid >> 6] = p;
        }
        __syncthreads();

        if (tid == 0) out[t] = red_sh[0] + red_sh[1] + bout;
        xcur = xnext;
    }
}

extern "C" void kernel_launch(void* const* d_in, const int* in_sizes, int n_in,
                              void* d_out, int out_size, void* d_ws, size_t ws_size,
                              hipStream_t stream) {
    const float* x     = (const float*)d_in[0];
    const float* h0    = (const float*)d_in[1];
    const float* c0    = (const float*)d_in[2];
    const float* W_ih  = (const float*)d_in[3];
    const float* W_hh  = (const float*)d_in[4];
    const float* b_ih  = (const float*)d_in[5];
    const float* b_hh  = (const float*)d_in[6];
    const float* W_out = (const float*)d_in[7];
    const float* b_out = (const float*)d_in[8];

    const size_t need = (size_t)S_LEN * HDIM * sizeof(_Float16);  // 16 MiB
    if (ws_size >= need) {
        _Float16* h_hist = (_Float16*)d_ws;
        lstm_seq_dot2<<<dim3(1), dim3(320), 0, stream>>>(
            x, h0, c0, W_ih, W_hh, b_ih, b_hh, h_hist);
        out_proj<<<dim3(1024), dim3(256), 0, stream>>>(
            h_hist, W_out, b_out, (float*)d_out);
    } else {
        lstm_seq_full<<<dim3(1), dim3(1024), 0, stream>>>(
            x, h0, c0, W_ih, W_hh, b_ih, b_hh, W_out, b_out, (float*)d_out);
    }
}